// Round 6
// baseline (581.321 us; speedup 1.0000x reference)
//
#include <hip/hip_runtime.h>
#include <hip/hip_bf16.h>
#include <stdint.h>

#define SEQ    2048
#define NBATCH 4
#define NHEADS 16
#define DHEAD  64
#define MODELD 1024
#define QKVN   1152          // 1024 q + 64 k + 64 v columns
#define MROWS  (NBATCH*SEQ)  // 8192
// exp(s*0.125) == exp2(s * 0.125 * log2(e)); folded into w_q at transpose time
#define SCALE_LOG2E 0.1803368801111244f

typedef __bf16 bf16x8 __attribute__((ext_vector_type(8)));
typedef float  f32x4  __attribute__((ext_vector_type(4)));

typedef __attribute__((address_space(1))) void* as1_void_p;
typedef __attribute__((address_space(3))) void* as3_void_p;

__device__ __forceinline__ void gld_lds16(const void* g, void* l) {
  __builtin_amdgcn_global_load_lds((as1_void_p)(g), (as3_void_p)(l), 16, 0, 0);
}

__device__ __forceinline__ ushort f2bf(float f) {
  union { float f; uint32_t i; } t; t.f = f;
  uint32_t r = (t.i + 0x7fffu + ((t.i >> 16) & 1u)) >> 16;
  return (ushort)r;
}
__device__ __forceinline__ uint32_t pack_bf16(float a, float b) {
  union { __hip_bfloat162 h2; uint32_t u; } cv;
  cv.h2 = __float22bfloat162_rn(make_float2(a, b));
  return cv.u;
}

// ---------------- fp32 -> bf16 bulk convert (x) ----------------
__global__ __launch_bounds__(256)
void f32_to_bf16(const float* __restrict__ src, ushort* __restrict__ dst) {
  const int i = (blockIdx.x * 256 + threadIdx.x) * 4;
  const float4 v = *(const float4*)(src + i);
  ushort4 o;
  o.x = f2bf(v.x); o.y = f2bf(v.y); o.z = f2bf(v.z); o.w = f2bf(v.w);
  *(ushort4*)(dst + i) = o;
}

// ------- weight transpose + convert + scale: dst[c][r] = bf16(src[r][c]*scale) -------
__global__ __launch_bounds__(256)
void transpose_f32_bf16(const float* __restrict__ src, ushort* __restrict__ dst,
                        int R, int C, float scale) {
  __shared__ float tile[32][33];
  const int tx = threadIdx.x & 31, ty = threadIdx.x >> 5;  // ty in 0..7
  const int c0 = blockIdx.x * 32, r0 = blockIdx.y * 32;
#pragma unroll
  for (int j = 0; j < 4; j++)
    tile[ty*4 + j][tx] = src[(size_t)(r0 + ty*4 + j) * C + c0 + tx];
  __syncthreads();
#pragma unroll
  for (int j = 0; j < 4; j++)
    dst[(size_t)(c0 + ty*4 + j) * R + r0 + tx] = f2bf(tile[tx][ty*4 + j] * scale);
}

// ---------------- GEMM: C(MxN) = A(MxK) * Bt(NxK)^T  (+bias), bf16 in --------
// m97 structure: 128x128 tile, BK=32, 4 waves, global_load_lds width-16 staging.
// VT!=nullptr: additionally write cols 1088..1151 transposed as vT[b][d][n] (bf16).
template <bool OUT_F32>
__global__ __launch_bounds__(256)
void gemm_bt(const ushort* __restrict__ A, const ushort* __restrict__ Bt,
             void* __restrict__ Cp, const float* __restrict__ bias,
             ushort* __restrict__ VT,
             int K, int lda, int ldb, int ldc) {
  __shared__ __attribute__((aligned(16))) ushort As[128*32];
  __shared__ __attribute__((aligned(16))) ushort Bs[128*32];
  const int tid = threadIdx.x;
  const int w = tid >> 6, lane = tid & 63;
  const int quad = lane >> 4, m16 = lane & 15;
  const int bm0 = blockIdx.y * 128, bn0 = blockIdx.x * 128;
  f32x4 acc[4][4] = {};

  const int ar0 = w*32 + (lane >> 2);
  const int ac0 = (lane & 3) * 8;
  const ushort* Ag = A  + (size_t)(bm0 + ar0) * lda + ac0;
  const ushort* Bg = Bt + (size_t)(bn0 + ar0) * ldb + ac0;
  ushort* AsW = As + (w*32)*32;   // wave-uniform base; HW adds lane*16B
  ushort* BsW = Bs + (w*32)*32;
  const int wm = (w >> 1) * 64, wn = (w & 1) * 64;

  for (int kb = 0; kb < K; kb += 32) {
    gld_lds16(Ag + kb,                   AsW);
    gld_lds16(Ag + (size_t)16*lda + kb,  AsW + 16*32);
    gld_lds16(Bg + kb,                   BsW);
    gld_lds16(Bg + (size_t)16*ldb + kb,  BsW + 16*32);
    __syncthreads();
    bf16x8 af[4], bfr[4];
#pragma unroll
    for (int mi = 0; mi < 4; mi++)
      af[mi] = *(const bf16x8*)(As + (wm + mi*16 + m16)*32 + quad*8);
#pragma unroll
    for (int ni = 0; ni < 4; ni++)
      bfr[ni] = *(const bf16x8*)(Bs + (wn + ni*16 + m16)*32 + quad*8);
#pragma unroll
    for (int mi = 0; mi < 4; mi++)
#pragma unroll
      for (int ni = 0; ni < 4; ni++)
        acc[mi][ni] = __builtin_amdgcn_mfma_f32_16x16x32_bf16(
            af[mi], bfr[ni], acc[mi][ni], 0, 0, 0);
    __syncthreads();
  }

  // epilogue: C/D layout col=lane&15, row=quad*4+reg
#pragma unroll
  for (int ni = 0; ni < 4; ni++) {
    const int col = bn0 + wn + ni*16 + m16;
    const float bv = bias ? bias[col] : 0.0f;
#pragma unroll
    for (int mi = 0; mi < 4; mi++) {
#pragma unroll
      for (int r = 0; r < 4; r++) {
        const int row = bm0 + wm + mi*16 + quad*4 + r;
        const float v = acc[mi][ni][r] + bv;
        if (OUT_F32) ((float*)Cp)[(size_t)row*ldc + col] = v;
        else         ((ushort*)Cp)[(size_t)row*ldc + col] = f2bf(v);
        if (VT && col >= 1088) {   // V columns -> transposed copy for attention
          const int d = col - 1088, bb = row >> 11, n = row & 2047;
          VT[((size_t)bb * DHEAD + d) * SEQ + n] = f2bf(v);
        }
      }
    }
  }
}

// ---------------- Flash MQA attention, v4 ----------------
// grid (SEQ/256, NHEADS, NBATCH), 256 threads = 4 waves, 64 Q rows per wave.
// KV chunk 64, processed in two 32-kv halves (halves the P buffer -> 4 blocks/CU).
// S^T = K Q^T (q pre-scaled by 0.125*log2e at weight transpose); p = v_exp_f32.
// Next chunk's K/V global loads issued right after staging (overlap full chunk).
__global__ __launch_bounds__(256, 4)
void mqa_attn(const ushort* __restrict__ qkv, const ushort* __restrict__ vT,
              ushort* __restrict__ attn_out) {
  __shared__ __attribute__((aligned(16))) ushort Ks[64*72];      // K[kv][d], pad 72
  __shared__ __attribute__((aligned(16))) ushort Vs[64*72];      // V^T[d][kv], pad 72
  __shared__ __attribute__((aligned(16))) ushort pbuf[4][64*40]; // per-wave P[q][32kv], pad 40

  const int tid = threadIdx.x;
  const int w = tid >> 6, lane = tid & 63;
  const int quad = lane >> 4, m16 = lane & 15;
  const int h = blockIdx.y, b = blockIdx.z;
  const size_t rowbase = (size_t)b * SEQ;
  const int q0 = blockIdx.x * 256 + w * 64;
  const ushort* vTb = vT + (size_t)b * DHEAD * SEQ;
  ushort* pb = pbuf[w];

  // staging map: thread covers (row = tid>>3, col = (tid&7)*8), 2 passes of 32 rows
  const int srow = tid >> 3, scol = (tid & 7) * 8;
  const ushort* kgbase = qkv + (rowbase + srow) * QKVN + 1024 + scol;
  const ushort* vgbase = vTb + (size_t)srow * SEQ + scol;

  // persistent Q fragments (B-layout: n=q=m16, k=d=kh*32+quad*8); q pre-scaled
  bf16x8 qf[4][2];
#pragma unroll
  for (int qt = 0; qt < 4; qt++) {
    const ushort* qrow = qkv + (rowbase + q0 + qt*16 + m16) * QKVN + h * DHEAD;
    qf[qt][0] = *(const bf16x8*)(qrow + quad*8);
    qf[qt][1] = *(const bf16x8*)(qrow + 32 + quad*8);
  }

  f32x4 o[4][4] = {};        // O^T tiles [qt][dt], C-layout: row=d=quad*4+r, col=q=m16
  float l_loc[4] = {};       // per-lane partial row sums (q=m16)

  // preload chunk 0
  uint4 kreg0 = *(const uint4*)(kgbase);
  uint4 kreg1 = *(const uint4*)(kgbase + (size_t)32 * QKVN);
  uint4 vreg0 = *(const uint4*)(vgbase);
  uint4 vreg1 = *(const uint4*)(vgbase + 32 * SEQ);

  for (int kv0 = 0; kv0 < SEQ; kv0 += 64) {
    __syncthreads();                         // prev chunk's readers done
    *(uint4*)(Ks + (srow     )*72 + scol) = kreg0;
    *(uint4*)(Ks + (srow + 32)*72 + scol) = kreg1;
    *(uint4*)(Vs + (srow     )*72 + scol) = vreg0;
    *(uint4*)(Vs + (srow + 32)*72 + scol) = vreg1;
    __syncthreads();                         // staging visible

    // issue NEXT chunk's global loads now (latency hidden behind this chunk)
    const int kvn = (kv0 + 64) & (SEQ - 1);
    kreg0 = *(const uint4*)(kgbase + (size_t)(kvn     ) * QKVN);
    kreg1 = *(const uint4*)(kgbase + (size_t)(kvn + 32) * QKVN);
    vreg0 = *(const uint4*)(vgbase + kvn);
    vreg1 = *(const uint4*)(vgbase + 32 * SEQ + kvn);

#pragma unroll
    for (int kh = 0; kh < 2; kh++) {
      // ---- S^T = K Q^T for this 32-kv half; p = exp2(s); P -> per-wave LDS ----
#pragma unroll
      for (int t2 = 0; t2 < 2; t2++) {
        const int t = kh*2 + t2;
        const bf16x8 kf0 = *(const bf16x8*)(Ks + (t*16 + m16)*72 + quad*8);
        const bf16x8 kf1 = *(const bf16x8*)(Ks + (t*16 + m16)*72 + 32 + quad*8);
#pragma unroll
        for (int qt = 0; qt < 4; qt++) {
          f32x4 s = {};
          s = __builtin_amdgcn_mfma_f32_16x16x32_bf16(kf0, qf[qt][0], s, 0, 0, 0);
          s = __builtin_amdgcn_mfma_f32_16x16x32_bf16(kf1, qf[qt][1], s, 0, 0, 0);
          float p[4];
#pragma unroll
          for (int r = 0; r < 4; r++) {
            p[r] = __builtin_amdgcn_exp2f(s[r]);   // kv=t*16+quad*4+r, q=m16
            l_loc[qt] += p[r];
          }
          *(uint2*)(pb + (qt*16 + m16)*40 + t2*16 + quad*4) =
              make_uint2(pack_bf16(p[0], p[1]), pack_bf16(p[2], p[3]));
        }
      }
      asm volatile("s_waitcnt lgkmcnt(0)" ::: "memory");  // wave-internal P RAW

      // ---- O^T += V^T[kh-slab] P^T[kh-slab] ----
      bf16x8 pf[4], vf[4];
#pragma unroll
      for (int qt = 0; qt < 4; qt++)
        pf[qt] = *(const bf16x8*)(pb + (qt*16 + m16)*40 + quad*8);
#pragma unroll
      for (int dt = 0; dt < 4; dt++)
        vf[dt] = *(const bf16x8*)(Vs + (dt*16 + m16)*72 + kh*32 + quad*8);
#pragma unroll
      for (int qt = 0; qt < 4; qt++)
#pragma unroll
        for (int dt = 0; dt < 4; dt++)
          o[qt][dt] = __builtin_amdgcn_mfma_f32_16x16x32_bf16(vf[dt], pf[qt], o[qt][dt], 0, 0, 0);
    }
  }

  // ---- epilogue: l over quads (kv partials), divide, packed 8B stores ----
#pragma unroll
  for (int qt = 0; qt < 4; qt++) {
    float l = l_loc[qt];
    l += __shfl_xor(l, 16, 64);
    l += __shfl_xor(l, 32, 64);
    const float inv = 1.0f / l;
    const size_t row = rowbase + q0 + qt*16 + m16;     // q = m16
#pragma unroll
    for (int dt = 0; dt < 4; dt++) {
      ushort4 st;
      st.x = f2bf(o[qt][dt][0] * inv);
      st.y = f2bf(o[qt][dt][1] * inv);
      st.z = f2bf(o[qt][dt][2] * inv);
      st.w = f2bf(o[qt][dt][3] * inv);
      *(ushort4*)(attn_out + row*MODELD + h*DHEAD + dt*16 + quad*4) = st;
    }
  }
}

// ---------------- launch ----------------
extern "C" void kernel_launch(void* const* d_in, const int* in_sizes, int n_in,
                              void* d_out, int out_size, void* d_ws, size_t ws_size,
                              hipStream_t stream) {
  // Reference dtypes: ALL inputs fp32, output fp32.
  const float* x     = (const float*)d_in[0];
  const float* w_q   = (const float*)d_in[1];
  const float* w_kv  = (const float*)d_in[2];
  const float* w_out = (const float*)d_in[3];
  const float* b_out = (const float*)d_in[4];

  ushort* wqkvT = (ushort*)d_ws;                         // 1152 x 1024 bf16
  ushort* woutT = wqkvT + (size_t)QKVN * MODELD;         // 1024 x 1024 bf16
  ushort* xb    = woutT + (size_t)MODELD * MODELD;       // 8192 x 1024 bf16
  ushort* qkv   = xb    + (size_t)MROWS * MODELD;        // 8192 x 1152 bf16
  ushort* attn  = qkv   + (size_t)MROWS * QKVN;          // 8192 x 1024 bf16
  ushort* vTb   = attn  + (size_t)MROWS * MODELD;        // 4 x 64 x 2048 bf16 (V^T)
  // total ws use ~59 MB

  // x -> bf16
  f32_to_bf16<<<(MROWS * MODELD) / 1024, 256, 0, stream>>>(x, xb);

  // weights -> B^T layout bf16; softmax scale folded into w_q
  transpose_f32_bf16<<<dim3(MODELD/32, MODELD/32), 256, 0, stream>>>(w_q,  wqkvT, MODELD, MODELD, SCALE_LOG2E);
  transpose_f32_bf16<<<dim3(128/32,    MODELD/32), 256, 0, stream>>>(w_kv, wqkvT + (size_t)MODELD * MODELD, MODELD, 128, 1.0f);
  transpose_f32_bf16<<<dim3(MODELD/32, MODELD/32), 256, 0, stream>>>(w_out, woutT, MODELD, MODELD, 1.0f);

  // fused QKV projection: (8192x1024) @ (1152x1024)^T -> 8192x1152 bf16 (+ V^T side-write)
  gemm_bt<false><<<dim3(QKVN/128, MROWS/128), 256, 0, stream>>>(
      xb, wqkvT, (void*)qkv, nullptr, vTb, MODELD, MODELD, MODELD, QKVN);

  // flash MQA -> attn (8192 x 1024 bf16, col = h*64+d)
  mqa_attn<<<dim3(SEQ/256, NHEADS, NBATCH), 256, 0, stream>>>(qkv, vTb, attn);

  // output projection + bias -> d_out (fp32)
  gemm_bt<true><<<dim3(MODELD/128, MROWS/128), 256, 0, stream>>>(
      attn, woutT, d_out, b_out, nullptr, MODELD, MODELD, MODELD, MODELD);
}

// Round 7
// 268.229 us; speedup vs baseline: 2.1673x; 2.1673x over previous
//
#include <hip/hip_runtime.h>
#include <hip/hip_bf16.h>
#include <stdint.h>

#define SEQ    2048
#define NBATCH 4
#define NHEADS 16
#define DHEAD  64
#define MODELD 1024
#define QKVN   1152          // 1024 q + 64 k + 64 v columns
#define MROWS  (NBATCH*SEQ)  // 8192
// exp(s*0.125) == exp2(s * 0.125 * log2(e)); folded into w_q at transpose time
#define SCALE_LOG2E 0.1803368801111244f

typedef __bf16 bf16x8 __attribute__((ext_vector_type(8)));
typedef float  f32x4  __attribute__((ext_vector_type(4)));

typedef __attribute__((address_space(1))) void* as1_void_p;
typedef __attribute__((address_space(3))) void* as3_void_p;

__device__ __forceinline__ void gld_lds16(const void* g, void* l) {
  __builtin_amdgcn_global_load_lds((as1_void_p)(g), (as3_void_p)(l), 16, 0, 0);
}

__device__ __forceinline__ ushort f2bf(float f) {
  union { float f; uint32_t i; } t; t.f = f;
  uint32_t r = (t.i + 0x7fffu + ((t.i >> 16) & 1u)) >> 16;
  return (ushort)r;
}
__device__ __forceinline__ uint32_t pack_bf16(float a, float b) {
  union { __hip_bfloat162 h2; uint32_t u; } cv;
  cv.h2 = __float22bfloat162_rn(make_float2(a, b));
  return cv.u;
}

// ---------------- fp32 -> bf16 bulk convert (x) ----------------
__global__ __launch_bounds__(256)
void f32_to_bf16(const float* __restrict__ src, ushort* __restrict__ dst) {
  const int i = (blockIdx.x * 256 + threadIdx.x) * 4;
  const float4 v = *(const float4*)(src + i);
  ushort4 o;
  o.x = f2bf(v.x); o.y = f2bf(v.y); o.z = f2bf(v.z); o.w = f2bf(v.w);
  *(ushort4*)(dst + i) = o;
}

// ------- weight transpose + convert + scale: dst[c][r] = bf16(src[r][c]*scale) -------
__global__ __launch_bounds__(256)
void transpose_f32_bf16(const float* __restrict__ src, ushort* __restrict__ dst,
                        int R, int C, float scale) {
  __shared__ float tile[32][33];
  const int tx = threadIdx.x & 31, ty = threadIdx.x >> 5;  // ty in 0..7
  const int c0 = blockIdx.x * 32, r0 = blockIdx.y * 32;
#pragma unroll
  for (int j = 0; j < 4; j++)
    tile[ty*4 + j][tx] = src[(size_t)(r0 + ty*4 + j) * C + c0 + tx];
  __syncthreads();
#pragma unroll
  for (int j = 0; j < 4; j++)
    dst[(size_t)(c0 + ty*4 + j) * R + r0 + tx] = f2bf(tile[tx][ty*4 + j] * scale);
}

// ---------------- GEMM: C(MxN) = A(MxK) * Bt(NxK)^T  (+bias), bf16 in --------
// m97 structure: 128x128 tile, BK=32, 4 waves, global_load_lds width-16 staging.
// VT!=nullptr: additionally write cols 1088..1151 transposed as vT[b][d][n] (bf16).
template <bool OUT_F32>
__global__ __launch_bounds__(256)
void gemm_bt(const ushort* __restrict__ A, const ushort* __restrict__ Bt,
             void* __restrict__ Cp, const float* __restrict__ bias,
             ushort* __restrict__ VT,
             int K, int lda, int ldb, int ldc) {
  __shared__ __attribute__((aligned(16))) ushort As[128*32];
  __shared__ __attribute__((aligned(16))) ushort Bs[128*32];
  const int tid = threadIdx.x;
  const int w = tid >> 6, lane = tid & 63;
  const int quad = lane >> 4, m16 = lane & 15;
  const int bm0 = blockIdx.y * 128, bn0 = blockIdx.x * 128;
  f32x4 acc[4][4] = {};

  const int ar0 = w*32 + (lane >> 2);
  const int ac0 = (lane & 3) * 8;
  const ushort* Ag = A  + (size_t)(bm0 + ar0) * lda + ac0;
  const ushort* Bg = Bt + (size_t)(bn0 + ar0) * ldb + ac0;
  ushort* AsW = As + (w*32)*32;   // wave-uniform base; HW adds lane*16B
  ushort* BsW = Bs + (w*32)*32;
  const int wm = (w >> 1) * 64, wn = (w & 1) * 64;

  for (int kb = 0; kb < K; kb += 32) {
    gld_lds16(Ag + kb,                   AsW);
    gld_lds16(Ag + (size_t)16*lda + kb,  AsW + 16*32);
    gld_lds16(Bg + kb,                   BsW);
    gld_lds16(Bg + (size_t)16*ldb + kb,  BsW + 16*32);
    __syncthreads();
    bf16x8 af[4], bfr[4];
#pragma unroll
    for (int mi = 0; mi < 4; mi++)
      af[mi] = *(const bf16x8*)(As + (wm + mi*16 + m16)*32 + quad*8);
#pragma unroll
    for (int ni = 0; ni < 4; ni++)
      bfr[ni] = *(const bf16x8*)(Bs + (wn + ni*16 + m16)*32 + quad*8);
#pragma unroll
    for (int mi = 0; mi < 4; mi++)
#pragma unroll
      for (int ni = 0; ni < 4; ni++)
        acc[mi][ni] = __builtin_amdgcn_mfma_f32_16x16x32_bf16(
            af[mi], bfr[ni], acc[mi][ni], 0, 0, 0);
    __syncthreads();
  }

  // epilogue: C/D layout col=lane&15, row=quad*4+reg
#pragma unroll
  for (int ni = 0; ni < 4; ni++) {
    const int col = bn0 + wn + ni*16 + m16;
    const float bv = bias ? bias[col] : 0.0f;
#pragma unroll
    for (int mi = 0; mi < 4; mi++) {
#pragma unroll
      for (int r = 0; r < 4; r++) {
        const int row = bm0 + wm + mi*16 + quad*4 + r;
        const float v = acc[mi][ni][r] + bv;
        if (OUT_F32) ((float*)Cp)[(size_t)row*ldc + col] = v;
        else         ((ushort*)Cp)[(size_t)row*ldc + col] = f2bf(v);
        if (VT && col >= 1088) {   // V columns -> transposed copy for attention
          const int d = col - 1088, bb = row >> 11, n = row & 2047;
          VT[((size_t)bb * DHEAD + d) * SEQ + n] = f2bf(v);
        }
      }
    }
  }
}

// ---------------- Flash MQA attention, v5 ----------------
// grid (SEQ/256, NHEADS, NBATCH), 256 threads = 4 waves, 64 Q rows per wave.
// KV chunk 64 in two 32-kv halves (P buffer halved -> 38.9 KB LDS -> 4 blocks/CU).
// launch_bounds(256,2): VGPR cap 256, compiler lands at ~128 (round-5-proven,
// no spill). (256,4) forced 64 VGPRs -> 1.4 GB scratch spill traffic (round 6).
__global__ __launch_bounds__(256, 2)
void mqa_attn(const ushort* __restrict__ qkv, const ushort* __restrict__ vT,
              ushort* __restrict__ attn_out) {
  __shared__ __attribute__((aligned(16))) ushort Ks[64*72];      // K[kv][d], pad 72
  __shared__ __attribute__((aligned(16))) ushort Vs[64*72];      // V^T[d][kv], pad 72
  __shared__ __attribute__((aligned(16))) ushort pbuf[4][64*40]; // per-wave P[q][32kv], pad 40

  const int tid = threadIdx.x;
  const int w = tid >> 6, lane = tid & 63;
  const int quad = lane >> 4, m16 = lane & 15;
  const int h = blockIdx.y, b = blockIdx.z;
  const size_t rowbase = (size_t)b * SEQ;
  const int q0 = blockIdx.x * 256 + w * 64;
  const ushort* vTb = vT + (size_t)b * DHEAD * SEQ;
  ushort* pb = pbuf[w];

  // staging map: thread covers (row = tid>>3, col = (tid&7)*8), 2 passes of 32 rows
  const int srow = tid >> 3, scol = (tid & 7) * 8;
  const ushort* kgbase = qkv + (rowbase + srow) * QKVN + 1024 + scol;
  const ushort* vgbase = vTb + (size_t)srow * SEQ + scol;

  // persistent Q fragments (B-layout: n=q=m16, k=d=kh*32+quad*8); q pre-scaled
  bf16x8 qf[4][2];
#pragma unroll
  for (int qt = 0; qt < 4; qt++) {
    const ushort* qrow = qkv + (rowbase + q0 + qt*16 + m16) * QKVN + h * DHEAD;
    qf[qt][0] = *(const bf16x8*)(qrow + quad*8);
    qf[qt][1] = *(const bf16x8*)(qrow + 32 + quad*8);
  }

  f32x4 o[4][4] = {};        // O^T tiles [qt][dt], C-layout: row=d=quad*4+r, col=q=m16
  float l_loc[4] = {};       // per-lane partial row sums (q=m16)

  // preload chunk 0
  uint4 kreg0 = *(const uint4*)(kgbase);
  uint4 kreg1 = *(const uint4*)(kgbase + (size_t)32 * QKVN);
  uint4 vreg0 = *(const uint4*)(vgbase);
  uint4 vreg1 = *(const uint4*)(vgbase + 32 * SEQ);

  for (int kv0 = 0; kv0 < SEQ; kv0 += 64) {
    __syncthreads();                         // prev chunk's readers done
    *(uint4*)(Ks + (srow     )*72 + scol) = kreg0;
    *(uint4*)(Ks + (srow + 32)*72 + scol) = kreg1;
    *(uint4*)(Vs + (srow     )*72 + scol) = vreg0;
    *(uint4*)(Vs + (srow + 32)*72 + scol) = vreg1;
    __syncthreads();                         // staging visible

    // issue NEXT chunk's global loads now (latency hidden behind this chunk)
    const int kvn = (kv0 + 64) & (SEQ - 1);
    kreg0 = *(const uint4*)(kgbase + (size_t)(kvn     ) * QKVN);
    kreg1 = *(const uint4*)(kgbase + (size_t)(kvn + 32) * QKVN);
    vreg0 = *(const uint4*)(vgbase + kvn);
    vreg1 = *(const uint4*)(vgbase + 32 * SEQ + kvn);

#pragma unroll
    for (int kh = 0; kh < 2; kh++) {
      // ---- S^T = K Q^T for this 32-kv half; p = exp2(s); P -> per-wave LDS ----
#pragma unroll
      for (int t2 = 0; t2 < 2; t2++) {
        const int t = kh*2 + t2;
        const bf16x8 kf0 = *(const bf16x8*)(Ks + (t*16 + m16)*72 + quad*8);
        const bf16x8 kf1 = *(const bf16x8*)(Ks + (t*16 + m16)*72 + 32 + quad*8);
#pragma unroll
        for (int qt = 0; qt < 4; qt++) {
          f32x4 s = {};
          s = __builtin_amdgcn_mfma_f32_16x16x32_bf16(kf0, qf[qt][0], s, 0, 0, 0);
          s = __builtin_amdgcn_mfma_f32_16x16x32_bf16(kf1, qf[qt][1], s, 0, 0, 0);
          float p[4];
#pragma unroll
          for (int r = 0; r < 4; r++) {
            p[r] = __builtin_amdgcn_exp2f(s[r]);   // kv=t*16+quad*4+r, q=m16
            l_loc[qt] += p[r];
          }
          *(uint2*)(pb + (qt*16 + m16)*40 + t2*16 + quad*4) =
              make_uint2(pack_bf16(p[0], p[1]), pack_bf16(p[2], p[3]));
        }
      }
      asm volatile("s_waitcnt lgkmcnt(0)" ::: "memory");  // wave-internal P RAW

      // ---- O^T += V^T[kh-slab] P^T[kh-slab] ----
      bf16x8 pf[4], vf[4];
#pragma unroll
      for (int qt = 0; qt < 4; qt++)
        pf[qt] = *(const bf16x8*)(pb + (qt*16 + m16)*40 + quad*8);
#pragma unroll
      for (int dt = 0; dt < 4; dt++)
        vf[dt] = *(const bf16x8*)(Vs + (dt*16 + m16)*72 + kh*32 + quad*8);
#pragma unroll
      for (int qt = 0; qt < 4; qt++)
#pragma unroll
        for (int dt = 0; dt < 4; dt++)
          o[qt][dt] = __builtin_amdgcn_mfma_f32_16x16x32_bf16(vf[dt], pf[qt], o[qt][dt], 0, 0, 0);
    }
  }

  // ---- epilogue: l over quads (kv partials), divide, packed 8B stores ----
#pragma unroll
  for (int qt = 0; qt < 4; qt++) {
    float l = l_loc[qt];
    l += __shfl_xor(l, 16, 64);
    l += __shfl_xor(l, 32, 64);
    const float inv = 1.0f / l;
    const size_t row = rowbase + q0 + qt*16 + m16;     // q = m16
#pragma unroll
    for (int dt = 0; dt < 4; dt++) {
      ushort4 st;
      st.x = f2bf(o[qt][dt][0] * inv);
      st.y = f2bf(o[qt][dt][1] * inv);
      st.z = f2bf(o[qt][dt][2] * inv);
      st.w = f2bf(o[qt][dt][3] * inv);
      *(ushort4*)(attn_out + row*MODELD + h*DHEAD + dt*16 + quad*4) = st;
    }
  }
}

// ---------------- launch ----------------
extern "C" void kernel_launch(void* const* d_in, const int* in_sizes, int n_in,
                              void* d_out, int out_size, void* d_ws, size_t ws_size,
                              hipStream_t stream) {
  // Reference dtypes: ALL inputs fp32, output fp32.
  const float* x     = (const float*)d_in[0];
  const float* w_q   = (const float*)d_in[1];
  const float* w_kv  = (const float*)d_in[2];
  const float* w_out = (const float*)d_in[3];
  const float* b_out = (const float*)d_in[4];

  ushort* wqkvT = (ushort*)d_ws;                         // 1152 x 1024 bf16
  ushort* woutT = wqkvT + (size_t)QKVN * MODELD;         // 1024 x 1024 bf16
  ushort* xb    = woutT + (size_t)MODELD * MODELD;       // 8192 x 1024 bf16
  ushort* qkv   = xb    + (size_t)MROWS * MODELD;        // 8192 x 1152 bf16
  ushort* attn  = qkv   + (size_t)MROWS * QKVN;          // 8192 x 1024 bf16
  ushort* vTb   = attn  + (size_t)MROWS * MODELD;        // 4 x 64 x 2048 bf16 (V^T)
  // total ws use ~59 MB

  // x -> bf16
  f32_to_bf16<<<(MROWS * MODELD) / 1024, 256, 0, stream>>>(x, xb);

  // weights -> B^T layout bf16; softmax scale folded into w_q
  transpose_f32_bf16<<<dim3(MODELD/32, MODELD/32), 256, 0, stream>>>(w_q,  wqkvT, MODELD, MODELD, SCALE_LOG2E);
  transpose_f32_bf16<<<dim3(128/32,    MODELD/32), 256, 0, stream>>>(w_kv, wqkvT + (size_t)MODELD * MODELD, MODELD, 128, 1.0f);
  transpose_f32_bf16<<<dim3(MODELD/32, MODELD/32), 256, 0, stream>>>(w_out, woutT, MODELD, MODELD, 1.0f);

  // fused QKV projection: (8192x1024) @ (1152x1024)^T -> 8192x1152 bf16 (+ V^T side-write)
  gemm_bt<false><<<dim3(QKVN/128, MROWS/128), 256, 0, stream>>>(
      xb, wqkvT, (void*)qkv, nullptr, vTb, MODELD, MODELD, MODELD, QKVN);

  // flash MQA -> attn (8192 x 1024 bf16, col = h*64+d)
  mqa_attn<<<dim3(SEQ/256, NHEADS, NBATCH), 256, 0, stream>>>(qkv, vTb, attn);

  // output projection + bias -> d_out (fp32)
  gemm_bt<true><<<dim3(MODELD/128, MROWS/128), 256, 0, stream>>>(
      attn, woutT, d_out, b_out, nullptr, MODELD, MODELD, MODELD, MODELD);
}

// Round 8
// 262.700 us; speedup vs baseline: 2.2129x; 1.0210x over previous
//
#include <hip/hip_runtime.h>
#include <hip/hip_bf16.h>
#include <stdint.h>

#define SEQ    2048
#define NBATCH 4
#define NHEADS 16
#define DHEAD  64
#define MODELD 1024
#define QKVN   1152          // 1024 q + 64 k + 64 v columns
#define MROWS  (NBATCH*SEQ)  // 8192
// exp(s*0.125) == exp2(s * 0.125 * log2(e)); folded into w_q at transpose time
#define SCALE_LOG2E 0.1803368801111244f

typedef __bf16 bf16x8 __attribute__((ext_vector_type(8)));
typedef float  f32x4  __attribute__((ext_vector_type(4)));

typedef __attribute__((address_space(1))) void* as1_void_p;
typedef __attribute__((address_space(3))) void* as3_void_p;

__device__ __forceinline__ void gld_lds16(const void* g, void* l) {
  __builtin_amdgcn_global_load_lds((as1_void_p)(g), (as3_void_p)(l), 16, 0, 0);
}

__device__ __forceinline__ ushort f2bf(float f) {
  union { float f; uint32_t i; } t; t.f = f;
  uint32_t r = (t.i + 0x7fffu + ((t.i >> 16) & 1u)) >> 16;
  return (ushort)r;
}
__device__ __forceinline__ uint32_t pack_bf16(float a, float b) {
  union { __hip_bfloat162 h2; uint32_t u; } cv;
  cv.h2 = __float22bfloat162_rn(make_float2(a, b));
  return cv.u;
}

// ---------------- fused prep: x convert + 3 weight transposes ----------------
// flat grid: [0,8192) x-convert; [8192,9216) w_q^T; [9216,9344) w_kv^T; [9344,10368) w_out^T
__device__ __forceinline__ void do_transpose(const float* __restrict__ src,
                                             ushort* __restrict__ dst,
                                             int R, int C, float scale,
                                             int gx, int gy, int tid) {
  __shared__ float tile[32][33];
  const int tx = tid & 31, ty = tid >> 5;  // ty in 0..7
  const int c0 = gx * 32, r0 = gy * 32;
#pragma unroll
  for (int j = 0; j < 4; j++)
    tile[ty*4 + j][tx] = src[(size_t)(r0 + ty*4 + j) * C + c0 + tx];
  __syncthreads();
#pragma unroll
  for (int j = 0; j < 4; j++)
    dst[(size_t)(c0 + ty*4 + j) * R + r0 + tx] = f2bf(tile[tx][ty*4 + j] * scale);
}

__global__ __launch_bounds__(256)
void prep(const float* __restrict__ x, const float* __restrict__ w_q,
          const float* __restrict__ w_kv, const float* __restrict__ w_out,
          ushort* __restrict__ xb, ushort* __restrict__ wqkvT,
          ushort* __restrict__ woutT) {
  const int bid = blockIdx.x, tid = threadIdx.x;
  if (bid < 8192) {                      // x -> bf16, 1024 elems/block
    const size_t i = ((size_t)bid * 256 + tid) * 4;
    const float4 v = *(const float4*)(x + i);
    ushort4 o;
    o.x = f2bf(v.x); o.y = f2bf(v.y); o.z = f2bf(v.z); o.w = f2bf(v.w);
    *(ushort4*)(xb + i) = o;
  } else if (bid < 9216) {               // w_q^T (scale folded)
    const int t = bid - 8192;
    do_transpose(w_q, wqkvT, MODELD, MODELD, SCALE_LOG2E, t & 31, t >> 5, tid);
  } else if (bid < 9344) {               // w_kv^T -> rows 1024..1151
    const int t = bid - 9216;
    do_transpose(w_kv, wqkvT + (size_t)MODELD * MODELD, MODELD, 128, 1.0f,
                 t & 3, t >> 2, tid);
  } else {                               // w_out^T
    const int t = bid - 9344;
    do_transpose(w_out, woutT, MODELD, MODELD, 1.0f, t & 31, t >> 5, tid);
  }
}

// ---------------- GEMM: C(MxN) = A(MxK) * Bt(NxK)^T  (+bias), bf16 in --------
// m97 structure: 128x128 tile, BK=32, 4 waves, global_load_lds width-16 staging.
// VT!=nullptr: additionally write cols 1088..1151 transposed as vT[b][d][n] (bf16).
template <bool OUT_F32>
__global__ __launch_bounds__(256)
void gemm_bt(const ushort* __restrict__ A, const ushort* __restrict__ Bt,
             void* __restrict__ Cp, const float* __restrict__ bias,
             ushort* __restrict__ VT,
             int K, int lda, int ldb, int ldc) {
  __shared__ __attribute__((aligned(16))) ushort As[128*32];
  __shared__ __attribute__((aligned(16))) ushort Bs[128*32];
  const int tid = threadIdx.x;
  const int w = tid >> 6, lane = tid & 63;
  const int quad = lane >> 4, m16 = lane & 15;
  const int bm0 = blockIdx.y * 128, bn0 = blockIdx.x * 128;
  f32x4 acc[4][4] = {};

  const int ar0 = w*32 + (lane >> 2);
  const int ac0 = (lane & 3) * 8;
  const ushort* Ag = A  + (size_t)(bm0 + ar0) * lda + ac0;
  const ushort* Bg = Bt + (size_t)(bn0 + ar0) * ldb + ac0;
  ushort* AsW = As + (w*32)*32;   // wave-uniform base; HW adds lane*16B
  ushort* BsW = Bs + (w*32)*32;
  const int wm = (w >> 1) * 64, wn = (w & 1) * 64;

  for (int kb = 0; kb < K; kb += 32) {
    gld_lds16(Ag + kb,                   AsW);
    gld_lds16(Ag + (size_t)16*lda + kb,  AsW + 16*32);
    gld_lds16(Bg + kb,                   BsW);
    gld_lds16(Bg + (size_t)16*ldb + kb,  BsW + 16*32);
    __syncthreads();
    bf16x8 af[4], bfr[4];
#pragma unroll
    for (int mi = 0; mi < 4; mi++)
      af[mi] = *(const bf16x8*)(As + (wm + mi*16 + m16)*32 + quad*8);
#pragma unroll
    for (int ni = 0; ni < 4; ni++)
      bfr[ni] = *(const bf16x8*)(Bs + (wn + ni*16 + m16)*32 + quad*8);
#pragma unroll
    for (int mi = 0; mi < 4; mi++)
#pragma unroll
      for (int ni = 0; ni < 4; ni++)
        acc[mi][ni] = __builtin_amdgcn_mfma_f32_16x16x32_bf16(
            af[mi], bfr[ni], acc[mi][ni], 0, 0, 0);
    __syncthreads();
  }

  // epilogue: C/D layout col=lane&15, row=quad*4+reg
  const bool blockHasV = (VT != nullptr) && (bn0 + 128 > 1088);
#pragma unroll
  for (int ni = 0; ni < 4; ni++) {
    const int col = bn0 + wn + ni*16 + m16;
    const float bv = bias ? bias[col] : 0.0f;
#pragma unroll
    for (int mi = 0; mi < 4; mi++) {
#pragma unroll
      for (int r = 0; r < 4; r++) {
        const int row = bm0 + wm + mi*16 + quad*4 + r;
        const float v = acc[mi][ni][r] + bv;
        if (OUT_F32) ((float*)Cp)[(size_t)row*ldc + col] = v;
        else         ((ushort*)Cp)[(size_t)row*ldc + col] = f2bf(v);
        if (blockHasV && col >= 1088) {  // V columns -> transposed copy
          const int d = col - 1088, bb = row >> 11, n = row & 2047;
          VT[((size_t)bb * DHEAD + d) * SEQ + n] = f2bf(v);
        }
      }
    }
  }
}

// ---------------- Flash MQA attention, v6 ----------------
// grid (SEQ/128, NHEADS, NBATCH) = 1024 blocks, 256 threads = 4 waves,
// 32 Q rows per wave. KV chunk 64 in two 32-kv halves.
// LDS 28.7 KB + ~90 VGPR -> 4 blocks/CU co-resident (grid-matched).
// launch_bounds(256,2): VGPR cap 256 (r6 lesson: min-waves=4 forces 64 VGPR -> spill).
__global__ __launch_bounds__(256, 2)
void mqa_attn(const ushort* __restrict__ qkv, const ushort* __restrict__ vT,
              ushort* __restrict__ attn_out) {
  __shared__ __attribute__((aligned(16))) ushort Ks[64*72];      // K[kv][d], pad 72
  __shared__ __attribute__((aligned(16))) ushort Vs[64*72];      // V^T[d][kv], pad 72
  __shared__ __attribute__((aligned(16))) ushort pbuf[4][32*40]; // per-wave P[q(32)][32kv], pad 40

  const int tid = threadIdx.x;
  const int w = tid >> 6, lane = tid & 63;
  const int quad = lane >> 4, m16 = lane & 15;
  const int h = blockIdx.y, b = blockIdx.z;
  const size_t rowbase = (size_t)b * SEQ;
  const int q0 = blockIdx.x * 128 + w * 32;
  const ushort* vTb = vT + (size_t)b * DHEAD * SEQ;
  ushort* pb = pbuf[w];

  // staging map: thread covers (row = tid>>3, col = (tid&7)*8), 2 passes of 32 rows
  const int srow = tid >> 3, scol = (tid & 7) * 8;
  const ushort* kgbase = qkv + (rowbase + srow) * QKVN + 1024 + scol;
  const ushort* vgbase = vTb + (size_t)srow * SEQ + scol;

  // persistent Q fragments (B-layout: n=q=m16, k=d=kh*32+quad*8); q pre-scaled
  bf16x8 qf[2][2];
#pragma unroll
  for (int qt = 0; qt < 2; qt++) {
    const ushort* qrow = qkv + (rowbase + q0 + qt*16 + m16) * QKVN + h * DHEAD;
    qf[qt][0] = *(const bf16x8*)(qrow + quad*8);
    qf[qt][1] = *(const bf16x8*)(qrow + 32 + quad*8);
  }

  f32x4 o[2][4] = {};        // O^T tiles [qt][dt], C-layout: row=d=quad*4+r, col=q=m16
  float l_loc[2] = {};       // per-lane partial row sums (q=m16)

  // preload chunk 0
  uint4 kreg0 = *(const uint4*)(kgbase);
  uint4 kreg1 = *(const uint4*)(kgbase + (size_t)32 * QKVN);
  uint4 vreg0 = *(const uint4*)(vgbase);
  uint4 vreg1 = *(const uint4*)(vgbase + 32 * SEQ);

  for (int kv0 = 0; kv0 < SEQ; kv0 += 64) {
    __syncthreads();                         // prev chunk's readers done
    *(uint4*)(Ks + (srow     )*72 + scol) = kreg0;
    *(uint4*)(Ks + (srow + 32)*72 + scol) = kreg1;
    *(uint4*)(Vs + (srow     )*72 + scol) = vreg0;
    *(uint4*)(Vs + (srow + 32)*72 + scol) = vreg1;
    __syncthreads();                         // staging visible

    // issue NEXT chunk's global loads now (latency hidden behind this chunk)
    const int kvn = (kv0 + 64) & (SEQ - 1);
    kreg0 = *(const uint4*)(kgbase + (size_t)(kvn     ) * QKVN);
    kreg1 = *(const uint4*)(kgbase + (size_t)(kvn + 32) * QKVN);
    vreg0 = *(const uint4*)(vgbase + kvn);
    vreg1 = *(const uint4*)(vgbase + 32 * SEQ + kvn);

#pragma unroll
    for (int kh = 0; kh < 2; kh++) {
      // ---- S^T = K Q^T for this 32-kv half; p = exp2(s); P -> per-wave LDS ----
#pragma unroll
      for (int t2 = 0; t2 < 2; t2++) {
        const int t = kh*2 + t2;
        const bf16x8 kf0 = *(const bf16x8*)(Ks + (t*16 + m16)*72 + quad*8);
        const bf16x8 kf1 = *(const bf16x8*)(Ks + (t*16 + m16)*72 + 32 + quad*8);
#pragma unroll
        for (int qt = 0; qt < 2; qt++) {
          f32x4 s = {};
          s = __builtin_amdgcn_mfma_f32_16x16x32_bf16(kf0, qf[qt][0], s, 0, 0, 0);
          s = __builtin_amdgcn_mfma_f32_16x16x32_bf16(kf1, qf[qt][1], s, 0, 0, 0);
          float p[4];
#pragma unroll
          for (int r = 0; r < 4; r++) {
            p[r] = __builtin_amdgcn_exp2f(s[r]);   // kv=t*16+quad*4+r, q=m16
            l_loc[qt] += p[r];
          }
          *(uint2*)(pb + (qt*16 + m16)*40 + t2*16 + quad*4) =
              make_uint2(pack_bf16(p[0], p[1]), pack_bf16(p[2], p[3]));
        }
      }
      asm volatile("s_waitcnt lgkmcnt(0)" ::: "memory");  // wave-internal P RAW

      // ---- O^T += V^T[kh-slab] P^T[kh-slab] ----
      bf16x8 pf[2], vf[4];
#pragma unroll
      for (int qt = 0; qt < 2; qt++)
        pf[qt] = *(const bf16x8*)(pb + (qt*16 + m16)*40 + quad*8);
#pragma unroll
      for (int dt = 0; dt < 4; dt++)
        vf[dt] = *(const bf16x8*)(Vs + (dt*16 + m16)*72 + kh*32 + quad*8);
#pragma unroll
      for (int qt = 0; qt < 2; qt++)
#pragma unroll
        for (int dt = 0; dt < 4; dt++)
          o[qt][dt] = __builtin_amdgcn_mfma_f32_16x16x32_bf16(vf[dt], pf[qt], o[qt][dt], 0, 0, 0);
    }
  }

  // ---- epilogue: l over quads (kv partials), divide, packed 8B stores ----
#pragma unroll
  for (int qt = 0; qt < 2; qt++) {
    float l = l_loc[qt];
    l += __shfl_xor(l, 16, 64);
    l += __shfl_xor(l, 32, 64);
    const float inv = 1.0f / l;
    const size_t row = rowbase + q0 + qt*16 + m16;     // q = m16
#pragma unroll
    for (int dt = 0; dt < 4; dt++) {
      ushort4 st;
      st.x = f2bf(o[qt][dt][0] * inv);
      st.y = f2bf(o[qt][dt][1] * inv);
      st.z = f2bf(o[qt][dt][2] * inv);
      st.w = f2bf(o[qt][dt][3] * inv);
      *(ushort4*)(attn_out + row*MODELD + h*DHEAD + dt*16 + quad*4) = st;
    }
  }
}

// ---------------- launch ----------------
extern "C" void kernel_launch(void* const* d_in, const int* in_sizes, int n_in,
                              void* d_out, int out_size, void* d_ws, size_t ws_size,
                              hipStream_t stream) {
  // Reference dtypes: ALL inputs fp32, output fp32.
  const float* x     = (const float*)d_in[0];
  const float* w_q   = (const float*)d_in[1];
  const float* w_kv  = (const float*)d_in[2];
  const float* w_out = (const float*)d_in[3];
  const float* b_out = (const float*)d_in[4];

  ushort* wqkvT = (ushort*)d_ws;                         // 1152 x 1024 bf16
  ushort* woutT = wqkvT + (size_t)QKVN * MODELD;         // 1024 x 1024 bf16
  ushort* xb    = woutT + (size_t)MODELD * MODELD;       // 8192 x 1024 bf16
  ushort* qkv   = xb    + (size_t)MROWS * MODELD;        // 8192 x 1152 bf16
  ushort* attn  = qkv   + (size_t)MROWS * QKVN;          // 8192 x 1024 bf16
  ushort* vTb   = attn  + (size_t)MROWS * MODELD;        // 4 x 64 x 2048 bf16 (V^T)
  // total ws use ~59 MB

  // fused prep: x->bf16 + 3 weight transposes (scale folded into w_q)
  prep<<<10368, 256, 0, stream>>>(x, w_q, w_kv, w_out, xb, wqkvT, woutT);

  // fused QKV projection: (8192x1024) @ (1152x1024)^T -> 8192x1152 bf16 (+ V^T side-write)
  gemm_bt<false><<<dim3(QKVN/128, MROWS/128), 256, 0, stream>>>(
      xb, wqkvT, (void*)qkv, nullptr, vTb, MODELD, MODELD, MODELD, QKVN);

  // flash MQA -> attn (8192 x 1024 bf16, col = h*64+d)
  mqa_attn<<<dim3(SEQ/128, NHEADS, NBATCH), 256, 0, stream>>>(qkv, vTb, attn);

  // output projection + bias -> d_out (fp32)
  gemm_bt<true><<<dim3(MODELD/128, MROWS/128), 256, 0, stream>>>(
      attn, woutT, d_out, b_out, nullptr, MODELD, MODELD, MODELD, MODELD);
}